// Round 1
// 359.848 us; speedup vs baseline: 1.2709x; 1.2709x over previous
//
#include <hip/hip_runtime.h>
#include <math.h>

#define S_ROWS 2047
#define DIM 256
#define HID 512
#define NHEADS 8
#define DH 32
#define NBINS 16
#define AFF_OUT 49

typedef short bf16x8 __attribute__((ext_vector_type(8)));
typedef float f32x4 __attribute__((ext_vector_type(4)));
typedef float f32x16 __attribute__((ext_vector_type(16)));
typedef unsigned short u16x8 __attribute__((ext_vector_type(8)));
typedef unsigned short u16x4 __attribute__((ext_vector_type(4)));

__device__ inline unsigned short f2b(float f) {
    unsigned int u = __float_as_uint(f);
    u += 0x7FFFu + ((u >> 16) & 1u);      // round-to-nearest-even
    return (unsigned short)(u >> 16);
}

// ---------------------------------------------------------------------------
// Fused setup: weight f32->bf16 conversion (+ew0 zero-pad to K=64),
// circular-feature embedding (bf16, 64-col padded), pos copy + out[6144]=0.
// One grid-stride kernel, phases by flat i4 index.
// ---------------------------------------------------------------------------
#define W_MAIN 3957248
#define EW0P_N 32768
#define P0 (W_MAIN / 4)                   // main weights (4 elems per i4)
#define P1 (P0 + EW0P_N / 4)              // ew0 padded
#define P2 (P1 + 2048 * 64 / 4)           // cond features
#define P3 (P2 + 1537)                    // pos copy (6148/4)
__global__ __launch_bounds__(256) void setup_kernel(
    const float* __restrict__ pos, const float* __restrict__ scale,
    const float* __restrict__ press, const float* __restrict__ temp,
    const float* __restrict__ e_w0, const float* __restrict__ p0,
    const float* __restrict__ p1, const float* __restrict__ p2,
    const float* __restrict__ p3, const float* __restrict__ p4,
    const float* __restrict__ p5, const float* __restrict__ p6,
    const float* __restrict__ p7, const float* __restrict__ p8,
    const float* __restrict__ p9, const float* __restrict__ p10,
    const float* __restrict__ p11, unsigned short* __restrict__ dst,
    unsigned short* __restrict__ cond, float* __restrict__ out)
{
    const int offs[13] = {0, 262144, 393216, 655360, 917504, 1179648, 1441792,
                          1966080, 3014656, 3538944, 3670016, 3932160, 3957248};
    const float* srcs[12] = {p0,p1,p2,p3,p4,p5,p6,p7,p8,p9,p10,p11};
    for (int i4 = blockIdx.x * blockDim.x + threadIdx.x; i4 < P3;
         i4 += gridDim.x * blockDim.x) {
        if (i4 < P0) {
            int e = i4 * 4;
            int s = 0;
            #pragma unroll
            for (int j = 1; j < 12; j++) s += (e >= offs[j]);
            const float4 v = *(const float4*)(srcs[s] + (e - offs[s]));
            u16x4 o;
            o[0] = f2b(v.x); o[1] = f2b(v.y); o[2] = f2b(v.z); o[3] = f2b(v.w);
            *(u16x4*)(dst + EW0P_N + e) = o;
        } else if (i4 < P1) {
            int e = (i4 - P0) * 4;
            u16x4 o;
            #pragma unroll
            for (int r = 0; r < 4; r++) {
                int ee = e + r;
                int row = ee >> 6, col = ee & 63;
                o[r] = (col < 35) ? f2b(e_w0[row * 35 + col]) : (unsigned short)0;
            }
            *(u16x4*)(dst + e) = o;
        } else if (i4 < P2) {
            int e = (i4 - P1) * 4;
            int row = e >> 6;
            u16x4 o;
            #pragma unroll
            for (int r = 0; r < 4; r++) {
                int c = (e + r) & 63;
                float v = 0.f;
                if (row < S_ROWS) {
                    if (c < 32) {
                        int coord = c >> 4;
                        int w = c & 15;
                        float x = pos[(row + 1) * 3 + coord];
                        float f = 6.283185307179586f * (float)((w & 7) + 1);
                        float ang = x * f;
                        v = (w < 8) ? cosf(ang) : sinf(ang);
                    } else if (c == 32) v = scale[0];
                    else if (c == 33) v = temp[0];
                    else if (c == 34) v = press[0];
                }
                o[r] = f2b(v);
            }
            *(u16x4*)(cond + e) = o;
        } else {
            int e = (i4 - P2) * 4;
            #pragma unroll
            for (int r = 0; r < 4; r++) {
                int ee = e + r;
                if (ee < 6144) out[ee] = pos[ee];
                else if (ee == 6144) out[ee] = 0.f;
            }
        }
    }
}

// ---------------------------------------------------------------------------
// bf16 MFMA GEMM, 64x32 tile (was 64x64): doubles grid.x so M=256 GEMMs fill
// all 256 CUs (was 128 blocks = half idle) and M=512 GEMMs get 2 blocks/CU
// (barrier stalls of one block hidden by the other). Register-prefetch
// pipeline kept. Per-wave: 16 rows x 32 cols, acc[2].
// ---------------------------------------------------------------------------
#define LDK 72
__global__ __launch_bounds__(256, 2) void gemm_bf16(
    const unsigned short* __restrict__ Ab, const unsigned short* __restrict__ W,
    const float* __restrict__ bias, const float* resF,
    float* Cf, unsigned short* Cb, int M, int K, int relu)
{
    __shared__ unsigned short As[64][LDK];
    __shared__ unsigned short Bs[32][LDK];
    int tid = threadIdx.x;
    int wave = tid >> 6, lane = tid & 63;
    int quad = lane >> 4, l16 = lane & 15;
    int row0 = blockIdx.y << 6, col0 = blockIdx.x << 5;
    int srow = tid >> 2, scol = (tid & 3) << 4;       // A stage: 64 rows x 64 k
    int srowB = tid >> 3, scolB = (tid & 7) << 3;     // B stage: 32 rows x 64 k

    f32x4 acc[2];
    #pragma unroll
    for (int i = 0; i < 2; i++) { f32x4 z = {0.f,0.f,0.f,0.f}; acc[i] = z; }

    const u16x8* ap = (const u16x8*)(Ab + (size_t)(row0 + srow) * K + scol);
    const u16x8* wp = (const u16x8*)(W + (size_t)(col0 + srowB) * K + scolB);
    u16x8 a0 = ap[0], a1 = ap[1];
    u16x8 b0 = wp[0];

    for (int k0 = 0; k0 < K; k0 += 64) {
        *(u16x8*)&As[srow][scol]     = a0;
        *(u16x8*)&As[srow][scol + 8] = a1;
        *(u16x8*)&Bs[srowB][scolB]   = b0;
        __syncthreads();
        if (k0 + 64 < K) {               // prefetch next tile (stays in flight)
            ap += 8; wp += 8;
            a0 = ap[0]; a1 = ap[1];
            b0 = wp[0];
        }
        #pragma unroll
        for (int kt = 0; kt < 64; kt += 32) {
            bf16x8 af = *(bf16x8*)&As[(wave << 4) + l16][kt + (quad << 3)];
            #pragma unroll
            for (int n0 = 0; n0 < 2; n0++) {
                bf16x8 bf = *(bf16x8*)&Bs[(n0 << 4) + l16][kt + (quad << 3)];
                acc[n0] = __builtin_amdgcn_mfma_f32_16x16x32_bf16(af, bf, acc[n0], 0, 0, 0);
            }
        }
        __syncthreads();
    }
    #pragma unroll
    for (int n0 = 0; n0 < 2; n0++) {
        int col = col0 + (n0 << 4) + l16;
        if (col >= M) continue;
        float bv = bias ? bias[col] : 0.f;
        #pragma unroll
        for (int r = 0; r < 4; r++) {
            int row = row0 + (wave << 4) + (quad << 2) + r;
            if (row >= S_ROWS) continue;
            float v = acc[n0][r] + bv;
            if (resF) v += resF[(size_t)row * M + col];
            if (relu) v = fmaxf(v, 0.f);
            if (Cf) Cf[(size_t)row * M + col] = v;
            if (Cb) Cb[(size_t)row * M + col] = f2b(v);
        }
    }
}

// ---------------------------------------------------------------------------
// Fused QKV GEMM (64x32 tile, register-prefetch) -> attention-native bf16
// layouts: qbh [h][q][d] (x 0.25506362 = 1/sqrt(32)*log2e), kbh [h][t][d]
// (+bk), vbT [h][d][t]. 32-col tiles keep each tile within one head.
// ---------------------------------------------------------------------------
__global__ __launch_bounds__(256, 2) void gemm_qkv(
    const unsigned short* __restrict__ Ab, const unsigned short* __restrict__ Wq,
    const unsigned short* __restrict__ Wk, const unsigned short* __restrict__ Wv,
    const float* __restrict__ bk,
    unsigned short* __restrict__ qbh, unsigned short* __restrict__ kbh,
    unsigned short* __restrict__ vbT)
{
    __shared__ unsigned short As[64][LDK];
    __shared__ unsigned short Bs[32][LDK];
    const int N = S_ROWS, K = 256;
    int tid = threadIdx.x;
    int wave = tid >> 6, lane = tid & 63;
    int quad = lane >> 4, l16 = lane & 15;
    int row0 = blockIdx.y << 6, col0 = blockIdx.x << 5;
    int mode = col0 >> 8;                 // 0=q 1=k 2=v
    int wcol0 = col0 & 255;
    const unsigned short* W = (mode == 0) ? Wq : (mode == 1) ? Wk : Wv;
    int srow = tid >> 2, scol = (tid & 3) << 4;
    int srowB = tid >> 3, scolB = (tid & 7) << 3;

    f32x4 acc[2];
    #pragma unroll
    for (int i = 0; i < 2; i++) { f32x4 z = {0.f,0.f,0.f,0.f}; acc[i] = z; }

    const u16x8* ap = (const u16x8*)(Ab + (size_t)(row0 + srow) * K + scol);
    const u16x8* wp = (const u16x8*)(W + (size_t)(wcol0 + srowB) * K + scolB);
    u16x8 a0 = ap[0], a1 = ap[1];
    u16x8 b0 = wp[0];

    for (int k0 = 0; k0 < K; k0 += 64) {
        *(u16x8*)&As[srow][scol]     = a0;
        *(u16x8*)&As[srow][scol + 8] = a1;
        *(u16x8*)&Bs[srowB][scolB]   = b0;
        __syncthreads();
        if (k0 + 64 < K) {
            ap += 8; wp += 8;
            a0 = ap[0]; a1 = ap[1];
            b0 = wp[0];
        }
        #pragma unroll
        for (int kt = 0; kt < 64; kt += 32) {
            bf16x8 af = *(bf16x8*)&As[(wave << 4) + l16][kt + (quad << 3)];
            #pragma unroll
            for (int n0 = 0; n0 < 2; n0++) {
                bf16x8 bf = *(bf16x8*)&Bs[(n0 << 4) + l16][kt + (quad << 3)];
                acc[n0] = __builtin_amdgcn_mfma_f32_16x16x32_bf16(af, bf, acc[n0], 0, 0, 0);
            }
        }
        __syncthreads();
    }
    #pragma unroll
    for (int n0 = 0; n0 < 2; n0++) {
        int colr = wcol0 + (n0 << 4) + l16;      // 0..255
        int hh = colr >> 5, d = colr & 31;
        int rbase = row0 + (wave << 4) + (quad << 2);
        if (mode == 2) {
            unsigned short* dst = vbT + ((size_t)hh * 32 + d) * 2048 + rbase;
            if (rbase + 3 < N) {
                u16x4 o;
                #pragma unroll
                for (int r = 0; r < 4; r++) o[r] = f2b(acc[n0][r]);
                *(u16x4*)dst = o;
            } else {
                #pragma unroll
                for (int r = 0; r < 4; r++)
                    if (rbase + r < N) dst[r] = f2b(acc[n0][r]);
            }
        } else {
            float bias = (mode == 1) ? bk[colr] : 0.f;
            unsigned short* dst = ((mode == 0) ? qbh : kbh) + (size_t)hh * 2048 * 32 + d;
            #pragma unroll
            for (int r = 0; r < 4; r++) {
                int row = rbase + r;
                if (row < N) {
                    float v = acc[n0][r] + bias;
                    if (mode == 0) v *= 0.25506362f;
                    dst[(size_t)row * 32] = f2b(v);
                }
            }
        }
    }
}

// ---------------------------------------------------------------------------
// MFMA flash attention with FUSED split-K combine. Block = 4 waves; wave w
// owns K-chunk w (512 keys). Partial (m,l,acc) combined through LDS; obb
// written directly (no part_o/part_ml global roundtrip, no combine kernel).
// Grid (64, 8) = 512 blocks = 2 blocks/CU = 8 waves/CU (same as before).
// ---------------------------------------------------------------------------
__global__ __launch_bounds__(256, 2) void attn_mfma(
    const unsigned short* __restrict__ qbh,
    const unsigned short* __restrict__ kbh,
    const unsigned short* __restrict__ vbT,
    unsigned short* __restrict__ obb)
{
    int tid = threadIdx.x;
    int w = tid >> 6;                     // wave = K-chunk
    int lane = tid & 63;
    int l31 = lane & 31, hf = lane >> 5;
    int q0 = blockIdx.x << 5;
    int h = blockIdx.y;
    int kstart = w * 512;
    int kend = min(kstart + 512, S_ROWS);

    const unsigned short* qp = qbh + ((size_t)h * 2048 + (q0 + l31)) * 32 + hf * 8;
    bf16x8 qf0 = *(const bf16x8*)(qp);
    bf16x8 qf1 = *(const bf16x8*)(qp + 16);

    const unsigned short* kb_h = kbh + (size_t)h * 2048 * 32;
    const unsigned short* vb_h = vbT + ((size_t)h * 32 + l31) * 2048;

    f32x16 acc = {};
    float m = -1e30f, l = 0.f;

    for (int key0 = kstart; key0 < kend; key0 += 32) {
        const unsigned short* kp = kb_h + (size_t)(key0 + l31) * 32 + hf * 8;
        bf16x8 kf0 = *(const bf16x8*)(kp);
        bf16x8 kf1 = *(const bf16x8*)(kp + 16);
        bf16x8 vf0 = *(const bf16x8*)(vb_h + key0 + hf * 8);
        bf16x8 vf1 = *(const bf16x8*)(vb_h + key0 + 16 + hf * 8);

        f32x16 sc = {};
        sc = __builtin_amdgcn_mfma_f32_32x32x16_bf16(kf0, qf0, sc, 0, 0, 0);
        sc = __builtin_amdgcn_mfma_f32_32x32x16_bf16(kf1, qf1, sc, 0, 0, 0);

        if (key0 + 32 > kend) {
            #pragma unroll
            for (int r = 0; r < 16; r++) {
                int kr = key0 + (r & 3) + 8 * (r >> 2) + 4 * hf;
                if (kr >= kend) sc[r] = -1e30f;
            }
        }
        float tmax = sc[0];
        #pragma unroll
        for (int r = 1; r < 16; r++) tmax = fmaxf(tmax, sc[r]);
        tmax = fmaxf(tmax, __shfl_xor(tmax, 32, 64));
        float mnew = fmaxf(m, tmax);
        float corr = __builtin_amdgcn_exp2f(m - mnew);
        m = mnew;
        float p[16];
        float ls = 0.f;
        #pragma unroll
        for (int r = 0; r < 16; r++) {
            p[r] = __builtin_amdgcn_exp2f(sc[r] - mnew);
            ls += p[r];
        }
        ls += __shfl_xor(ls, 32, 64);
        l = l * corr + ls;
        if (__ballot(corr != 1.0f)) {
            #pragma unroll
            for (int r = 0; r < 16; r++) acc[r] *= corr;
        }
        unsigned int pk[8];
        #pragma unroll
        for (int i = 0; i < 8; i++)
            pk[i] = __builtin_amdgcn_perm(__float_as_uint(p[2*i+1]),
                                          __float_as_uint(p[2*i]), 0x07060302u);
        unsigned int x[8];
        #pragma unroll
        for (int i = 0; i < 8; i++)
            x[i] = (unsigned int)__shfl_xor((int)pk[i], 32, 64);
        union { unsigned int u[4]; bf16x8 v; } B1, B2;
        B1.u[0] = hf ? x[2]  : pk[0];
        B1.u[1] = hf ? x[3]  : pk[1];
        B1.u[2] = hf ? pk[2] : x[0];
        B1.u[3] = hf ? pk[3] : x[1];
        B2.u[0] = hf ? x[6]  : pk[4];
        B2.u[1] = hf ? x[7]  : pk[5];
        B2.u[2] = hf ? pk[6] : x[4];
        B2.u[3] = hf ? pk[7] : x[5];
        acc = __builtin_amdgcn_mfma_f32_32x32x16_bf16(vf0, B1.v, acc, 0, 0, 0);
        acc = __builtin_amdgcn_mfma_f32_32x32x16_bf16(vf1, B2.v, acc, 0, 0, 0);
    }

    // ---- in-block split-K combine through LDS ----
    __shared__ float sm_m[4][32];
    __shared__ float sm_l[4][32];
    __shared__ float sm_acc[4][32][36];   // [chunk][q][d], pad 36 vs bank hits
    if (!hf) { sm_m[w][l31] = m; sm_l[w][l31] = l; }
    #pragma unroll
    for (int g = 0; g < 4; g++) {
        float4 o4;
        o4.x = acc[4*g]; o4.y = acc[4*g+1]; o4.z = acc[4*g+2]; o4.w = acc[4*g+3];
        *(float4*)&sm_acc[w][l31][8*g + 4*hf] = o4;
    }
    __syncthreads();

    int q = tid & 31;                     // query within block
    int dg = tid >> 5;                    // dim group 0..7 (4 dims each)
    float mmax = fmaxf(fmaxf(sm_m[0][q], sm_m[1][q]),
                       fmaxf(sm_m[2][q], sm_m[3][q]));
    float lsum = 0.f;
    float num0 = 0.f, num1 = 0.f, num2 = 0.f, num3 = 0.f;
    #pragma unroll
    for (int c = 0; c < 4; c++) {
        float wgt = __builtin_amdgcn_exp2f(sm_m[c][q] - mmax);
        lsum += sm_l[c][q] * wgt;
        float4 o4 = *(const float4*)&sm_acc[c][q][dg * 4];
        num0 = fmaf(o4.x, wgt, num0);
        num1 = fmaf(o4.y, wgt, num1);
        num2 = fmaf(o4.z, wgt, num2);
        num3 = fmaf(o4.w, wgt, num3);
    }
    float inv = 1.f / lsum;
    if (q0 + q < S_ROWS) {
        u16x4 st;
        st[0] = f2b(num0 * inv); st[1] = f2b(num1 * inv);
        st[2] = f2b(num2 * inv); st[3] = f2b(num3 * inv);
        *(u16x4*)(obb + (size_t)(q0 + q) * DIM + h * DH + dg * 4) = st;
    }
}

// ---------------------------------------------------------------------------
// RQS spline, register-only, wave-level logdet reduce + atomicAdd to out[6144].
// 64-thread blocks x 32 blocks (spread over more CUs than old 8x256).
// ---------------------------------------------------------------------------
__global__ __launch_bounds__(64) void spline_kernel(const float* __restrict__ pos,
    const float* __restrict__ params, float* __restrict__ out)
{
    int r = blockIdx.x * 64 + threadIdx.x;
    float ld = 0.f;
    if (r < S_ROWS) {
        const float* p = params + (size_t)r * AFF_OUT;
        float x = pos[(r + 1) * 3 + 2];
        float xc = fminf(fmaxf(x, 0.f), 1.f);

        float mw = -1e30f, mh = -1e30f;
        #pragma unroll
        for (int j = 0; j < NBINS; j++) {
            mw = fmaxf(mw, p[j]);
            mh = fmaxf(mh, p[NBINS + j]);
        }
        float sw = 0.f, sh = 0.f;
        #pragma unroll
        for (int j = 0; j < NBINS; j++) {
            sw += __expf(p[j] - mw);
            sh += __expf(p[NBINS + j] - mh);
        }
        const float span = 1.0f - NBINS * 1e-4f;
        float scw = span / sw, sch = span / sh;

        float cumw = 0.f, cumh = 0.f;
        float xk = 0.f, yk = 0.f, wk = 0.f, hk = 0.f;
        int k = 0;
        #pragma unroll
        for (int j = 0; j < NBINS; j++) {
            float wj = __expf(p[j] - mw) * scw + 1e-4f;
            float hj = __expf(p[NBINS + j] - mh) * sch + 1e-4f;
            if (xc >= cumw) { k = j; xk = cumw; yk = cumh; wk = wj; hk = hj; }
            cumw += wj; cumh += hj;
        }
        float offset = logf(expm1f(0.9999f));
        float t0 = p[2 * NBINS + k] + offset;
        float t1 = ((k == NBINS - 1) ? p[2 * NBINS] : p[2 * NBINS + k + 1]) + offset;
        float dk  = ((t0 > 15.f) ? t0 : log1pf(__expf(t0))) + 1e-4f;
        float dk1 = ((t1 > 15.f) ? t1 : log1pf(__expf(t1))) + 1e-4f;

        float sl = hk / wk;
        float z = (xc - xk) / wk;
        float z1 = 1.f - z;
        float den = sl + (dk1 + dk - 2.f * sl) * z * z1;
        float y = yk + hk * (sl * z * z + dk * z * z1) / den;
        float ldv = 2.f * logf(sl)
                  + logf(dk1 * z * z + 2.f * sl * z * z1 + dk * z1 * z1)
                  - 2.f * logf(den);
        bool inside = (x >= 0.f) && (x <= 1.f);
        y = inside ? y : x;
        ld = inside ? ldv : 0.f;
        out[(r + 1) * 3 + 2] = y;
    }
    #pragma unroll
    for (int st = 32; st > 0; st >>= 1) ld += __shfl_xor(ld, st, 64);
    if (threadIdx.x == 0) atomicAdd(&out[6144], ld);
}

// ---------------------------------------------------------------------------
extern "C" void kernel_launch(void* const* d_in, const int* in_sizes, int n_in,
                              void* d_out, int out_size, void* d_ws, size_t ws_size,
                              hipStream_t stream)
{
    const float* pos   = (const float*)d_in[0];
    const float* scale = (const float*)d_in[1];
    const float* press = (const float*)d_in[2];
    const float* temp  = (const float*)d_in[3];
    const float* e_w0  = (const float*)d_in[4];
    const float* e_b0  = (const float*)d_in[5];
    const float* e_w1  = (const float*)d_in[6];
    const float* e_b1  = (const float*)d_in[7];
    const float* e_w2  = (const float*)d_in[8];
    const float* e_b2  = (const float*)d_in[9];
    const float* Wq    = (const float*)d_in[10];
    const float* Wk    = (const float*)d_in[11];
    const float* bk    = (const float*)d_in[12];
    const float* Wv    = (const float*)d_in[13];
    const float* Wo    = (const float*)d_in[14];
    const float* bo    = (const float*)d_in[15];
    const float* mw0   = (const float*)d_in[16];
    const float* mb0   = (const float*)d_in[17];
    const float* mw1   = (const float*)d_in[18];
    const float* mb1   = (const float*)d_in[19];
    const float* mw2   = (const float*)d_in[20];
    const float* mb2   = (const float*)d_in[21];
    const float* a_w0  = (const float*)d_in[22];
    const float* a_b0  = (const float*)d_in[23];
    const float* a_w1  = (const float*)d_in[24];
    const float* a_b1  = (const float*)d_in[25];
    const float* a_w2  = (const float*)d_in[26];
    const float* a_b2  = (const float*)d_in[27];
    float* out = (float*)d_out;

    // bf16 weight region offsets (u16 elements): [ew0p | main segments]
    enum { OFF_EW0 = 0,
           OFF_EW1 = 32768 + 0,       OFF_EW2 = 32768 + 262144,
           OFF_WQ  = 32768 + 393216,  OFF_WK  = 32768 + 655360,
           OFF_WV  = 32768 + 917504,  OFF_WO  = 32768 + 1179648,
           OFF_MW0 = 32768 + 1441792, OFF_MW1 = 32768 + 1966080,
           OFF_MW2 = 32768 + 3014656, OFF_AW0 = 32768 + 3538944,
           OFF_AW1 = 32768 + 3670016, OFF_AW2 = 32768 + 3932160 };
    const size_t WB_U16 = (size_t)EW0P_N + W_MAIN;   // 3990016

    float* ws = (float*)d_ws;
    size_t off = 0;
    float* hbuf = ws + off; off += 2048 * 256;             // f32 residual stream
    float* pr   = ws + off; off += 2048 * 64;              // spline params f32
    unsigned short* wbp   = (unsigned short*)(ws + off); off += WB_U16 / 2;
    unsigned short* cond  = (unsigned short*)(ws + off); off += 2048 * 64 / 2;
    unsigned short* t1b   = (unsigned short*)(ws + off); off += 2048 * 512 / 2;
    unsigned short* t2b   = (unsigned short*)(ws + off); off += 2048 * 512 / 2;
    unsigned short* hb    = (unsigned short*)(ws + off); off += 2048 * 256 / 2;
    unsigned short* obb   = (unsigned short*)(ws + off); off += 2048 * 256 / 2;
    unsigned short* qbh   = (unsigned short*)(ws + off); off += NHEADS * 2048 * 32 / 2;
    unsigned short* kbh   = (unsigned short*)(ws + off); off += NHEADS * 2048 * 32 / 2;
    unsigned short* vbT   = (unsigned short*)(ws + off); off += NHEADS * 2048 * 32 / 2;
    (void)ws_size;

    dim3 b256(256);
    hipLaunchKernelGGL(setup_kernel, dim3(1024), b256, 0, stream,
                       pos, scale, press, temp, e_w0,
                       e_w1, e_w2, Wq, Wk, Wv, Wo, mw0, mw1, mw2,
                       a_w0, a_w1, a_w2, wbp, cond, out);

    auto gemm = [&](const unsigned short* A, const unsigned short* W,
                    const float* bias, const float* resF, float* Cf,
                    unsigned short* Cb, int M, int K, int relu) {
        dim3 grid((M + 31) / 32, 32);
        hipLaunchKernelGGL(gemm_bf16, grid, dim3(256), 0, stream,
                           A, W, bias, resF, Cf, Cb, M, K, relu);
    };

    // embedding MLP: 35(->64) -> 512 -> 512 -> 256
    gemm(cond, wbp + OFF_EW0, e_b0, nullptr, nullptr, t1b, 512, 64, 1);
    gemm(t1b,  wbp + OFF_EW1, e_b1, nullptr, nullptr, t2b, 512, 512, 1);
    gemm(t2b,  wbp + OFF_EW2, e_b2, nullptr, hbuf, hb, 256, 512, 0);

    for (int l = 0; l < 4; l++) {
        hipLaunchKernelGGL(gemm_qkv, dim3(24, 32), b256, 0, stream,
                           hb, wbp + OFF_WQ + l * 65536, wbp + OFF_WK + l * 65536,
                           wbp + OFF_WV + l * 65536, bk + l * 256, qbh, kbh, vbT);
        hipLaunchKernelGGL(attn_mfma, dim3(64, NHEADS), b256, 0, stream,
                           qbh, kbh, vbT, obb);
        gemm(obb, wbp + OFF_WO + l * 65536, bo + l * 256, hbuf, hbuf, hb, 256, 256, 0);
        gemm(hb,  wbp + OFF_MW0 + l * 131072, mb0 + l * 512, nullptr, nullptr, t1b, 512, 256, 1);
        gemm(t1b, wbp + OFF_MW1 + l * 262144, mb1 + l * 512, nullptr, nullptr, t2b, 512, 512, 1);
        gemm(t2b, wbp + OFF_MW2 + l * 131072, mb2 + l * 256, hbuf, hbuf, hb, 256, 512, 0);
    }

    // affine-param MLP: 256 -> 512 -> 512 -> 49
    gemm(hb,  wbp + OFF_AW0, a_b0, nullptr, nullptr, t1b, 512, 256, 1);
    gemm(t1b, wbp + OFF_AW1, a_b1, nullptr, nullptr, t2b, 512, 512, 1);
    gemm(t2b, wbp + OFF_AW2, a_b2, nullptr, pr, nullptr, AFF_OUT, 512, 0);

    hipLaunchKernelGGL(spline_kernel, dim3(32), dim3(64), 0, stream, pos, pr, out);
}